// Round 23
// baseline (141.614 us; speedup 1.0000x reference)
//
#include <hip/hip_runtime.h>

// IncrementalRobertaSelfAttentionCross: B=4, Sq=1024, Skv=2048 (enc||dec), D=1024, H=16, HD=64
// Pipeline: prep (Wt transpose + A cast) -> fused QKV GEMM (128x256 tile, 8 waves,
//           static triple-buffer + counted vmcnt(6)) -> flash attn (dual-tile pipeline, r22).

typedef _Float16 f16;
typedef __attribute__((ext_vector_type(4))) _Float16 half4;
typedef __attribute__((ext_vector_type(8))) _Float16 half8;
typedef __attribute__((ext_vector_type(4))) float floatx4;
typedef __attribute__((ext_vector_type(16))) float floatx16;
typedef __attribute__((ext_vector_type(4))) unsigned int uint4v;

#define GLOAD16(gp, lp)                                                        \
    __builtin_amdgcn_global_load_lds(                                          \
        (const __attribute__((address_space(1))) void*)(gp),                   \
        (__attribute__((address_space(3))) void*)(lp), 16, 0, 0)

// ---------------------------------------------------------------- prep: W transposes + A cast
__global__ void prep_kernel(const float* __restrict__ hid, const float* __restrict__ enc,
                            const float* __restrict__ Wq, const float* __restrict__ Wk,
                            const float* __restrict__ Wv, f16* __restrict__ Wtq,
                            f16* __restrict__ Wtk, f16* __restrict__ Wtv,
                            f16* __restrict__ Aall) {
    int bid = blockIdx.x, tid = threadIdx.x;
    if (bid < 3072) {
        __shared__ float tile[32][33];
        int z = bid >> 10, xy = bid & 1023;
        const float* W = (z == 0) ? Wq : (z == 1) ? Wk : Wv;
        f16* Wt = (z == 0) ? Wtq : (z == 1) ? Wtk : Wtv;
        int n0 = (xy & 31) * 32, k0 = (xy >> 5) * 32;
        int tx = tid & 31, ty = tid >> 5;   // (32,8)
        #pragma unroll
        for (int i = 0; i < 32; i += 8)
            tile[ty + i][tx] = W[(k0 + ty + i) * 1024 + n0 + tx];
        __syncthreads();
        #pragma unroll
        for (int i = 0; i < 32; i += 8)
            Wt[(n0 + ty + i) * 1024 + k0 + tx] = (f16)tile[tx][ty + i];
    } else {
        int t = (bid - 3072) * 256 + tid;
        int rowg = t >> 7, col = (t & 127) * 8;
        int b = rowg >> 11, r = rowg & 2047;
        const float* src = (r < 1024 ? enc + ((size_t)b * 1024 + r) * 1024
                                     : hid + ((size_t)b * 1024 + (r - 1024)) * 1024) + col;
        float4 v0 = *(const float4*)src, v1 = *(const float4*)(src + 4);
        half8 o;
        o[0] = (f16)v0.x; o[1] = (f16)v0.y; o[2] = (f16)v0.z; o[3] = (f16)v0.w;
        o[4] = (f16)v1.x; o[5] = (f16)v1.y; o[6] = (f16)v1.z; o[7] = (f16)v1.w;
        *(half8*)(Aall + (size_t)rowg * 1024 + col) = o;
    }
}

// ---------------------------------------------------------------- fused QKV GEMM (128x256, 8 waves)
// z=0: Q -> [bh][s][64] (x<32); z=1: K -> [bh][s][64]; z=2: V -> [bh][d][s] (V^T)
// Static triple-buffer; per stage 3 loads (1 A + 2 B); counted vmcnt(6): waited tile's
// loads are 2 phases old. Source-swizzled staging + matching read offset (conflict-free).
__launch_bounds__(512)
__global__ void qkv_gemm(const f16* __restrict__ Aall,
                         const f16* __restrict__ Wtq, const f16* __restrict__ Wtk,
                         const f16* __restrict__ Wtv,
                         const float* __restrict__ bq, const float* __restrict__ bk,
                         const float* __restrict__ bv,
                         f16* __restrict__ Qw, f16* __restrict__ Kw, f16* __restrict__ Vtw) {
    int mode = blockIdx.z;
    if (mode == 0 && blockIdx.x >= 32) return;   // uniform per block: barrier-safe
    __shared__ f16 As0[128 * 32];
    __shared__ f16 Bs0[256 * 32];
    __shared__ f16 As1[128 * 32];
    __shared__ f16 Bs1[256 * 32];
    __shared__ f16 As2[128 * 32];
    __shared__ f16 Bs2[256 * 32];

    const f16* Wt = (mode == 0) ? Wtq : (mode == 1) ? Wtk : Wtv;
    const float* bias = (mode == 0) ? bq : (mode == 1) ? bk : bv;
    f16* out = (mode == 0) ? Qw : (mode == 1) ? Kw : Vtw;

    int tid = threadIdx.x;
    int m0 = blockIdx.x * 128, n0 = blockIdx.y * 256;
    int wid = tid >> 6, lane = tid & 63;
    int wm = (wid >> 2) * 64, wn = (wid & 3) * 64;
    int lr = lane & 15, lg = lane >> 4;

    floatx4 acc[4][4];
    #pragma unroll
    for (int i = 0; i < 4; i++)
        #pragma unroll
        for (int j = 0; j < 4; j++) acc[i][j] = (floatx4)(0.f);

    // staging: thread t covers A row (t>>2) and B rows (t>>2), (t>>2)+128;
    // source chunk swizzled by (row>>1)&3 == (tid>>3)&3 (same for row+128: 128%4==0)
    int trow = tid >> 2;
    int tcol = (((tid & 3) ^ ((tid >> 3) & 3))) * 8;
    const f16* ag;
    {
        int mA = m0 + trow;
        if (mode == 0) {
            int b0 = mA >> 10;
            ag = Aall + ((size_t)(b0 * 2048 + 1024 + (mA & 1023))) * 1024 + tcol;
        } else {
            ag = Aall + (size_t)mA * 1024 + tcol;
        }
    }
    const f16* b0g = Wt + (size_t)(n0 + trow) * 1024 + tcol;
    const f16* b1g = Wt + (size_t)(n0 + trow + 128) * 1024 + tcol;

    // read-side swizzled column offset: (lg ^ ((lr>>1)&3)) * 8 halves
    int rcol = (lg ^ ((lr >> 1) & 3)) * 8;

    #define QKV_STAGE(off, Abuf, Bbuf)                    \
        GLOAD16(ag + (off), &Abuf[tid * 8]);              \
        GLOAD16(b0g + (off), &Bbuf[tid * 8]);             \
        GLOAD16(b1g + (off), &Bbuf[tid * 8 + 4096]);

    #define QKV_COMPUTE(Abuf, Bbuf)                                                       \
        {                                                                                 \
            half8 a[4], bf[4];                                                            \
            _Pragma("unroll")                                                             \
            for (int i = 0; i < 4; i++)                                                   \
                a[i] = *(const half8*)&Abuf[(wm + i * 16 + lr) * 32 + rcol];              \
            _Pragma("unroll")                                                             \
            for (int j = 0; j < 4; j++)                                                   \
                bf[j] = *(const half8*)&Bbuf[(wn + j * 16 + lr) * 32 + rcol];             \
            __builtin_amdgcn_s_setprio(1);                                                \
            _Pragma("unroll")                                                             \
            for (int i = 0; i < 4; i++)                                                   \
                _Pragma("unroll")                                                         \
                for (int j = 0; j < 4; j++)                                               \
                    acc[i][j] = __builtin_amdgcn_mfma_f32_16x16x32_f16(a[i], bf[j],       \
                                                                      acc[i][j], 0, 0, 0);\
            __builtin_amdgcn_s_setprio(0);                                                \
        }

    // prologue: stage tiles 0,32,64 -> buf0,1,2 (9 loads); wait tile0 (6 in flight); barrier
    QKV_STAGE(0,  As0, Bs0);
    QKV_STAGE(32, As1, Bs1);
    QKV_STAGE(64, As2, Bs2);
    asm volatile("s_waitcnt vmcnt(6)" ::: "memory");
    __builtin_amdgcn_s_barrier();

    // main: 10 groups x 3 tiles; invariant: current tile ready, next two outstanding (6 loads)
    for (int k0 = 0; k0 < 960; k0 += 96) {
        QKV_COMPUTE(As0, Bs0);                                    // tile k0
        asm volatile("s_waitcnt lgkmcnt(0)" ::: "memory");
        __builtin_amdgcn_s_barrier();
        QKV_STAGE(k0 + 96, As0, Bs0);
        asm volatile("s_waitcnt vmcnt(6)" ::: "memory");          // tile k0+32 done
        __builtin_amdgcn_s_barrier();

        QKV_COMPUTE(As1, Bs1);                                    // tile k0+32
        asm volatile("s_waitcnt lgkmcnt(0)" ::: "memory");
        __builtin_amdgcn_s_barrier();
        QKV_STAGE(k0 + 128, As1, Bs1);
        asm volatile("s_waitcnt vmcnt(6)" ::: "memory");          // tile k0+64 done
        __builtin_amdgcn_s_barrier();

        QKV_COMPUTE(As2, Bs2);                                    // tile k0+64
        asm volatile("s_waitcnt lgkmcnt(0)" ::: "memory");
        __builtin_amdgcn_s_barrier();
        if (k0 + 160 < 1024) {
            QKV_STAGE(k0 + 160, As2, Bs2);
            asm volatile("s_waitcnt vmcnt(6)" ::: "memory");      // tile k0+96 done
        } else {
            asm volatile("s_waitcnt vmcnt(3)" ::: "memory");      // tile 960 done (992 in flight)
        }
        __builtin_amdgcn_s_barrier();
    }

    // tail: tiles 960 (buf0), 992 (buf1)
    QKV_COMPUTE(As0, Bs0);
    asm volatile("s_waitcnt vmcnt(0)" ::: "memory");
    __builtin_amdgcn_s_barrier();
    QKV_COMPUTE(As1, Bs1);

    #undef QKV_STAGE
    #undef QKV_COMPUTE

    if (mode == 2) {
        #pragma unroll
        for (int i = 0; i < 4; i++) {
            int mbase = m0 + wm + i * 16 + lg * 4;
            int b = mbase >> 11, s = mbase & 2047;
            #pragma unroll
            for (int j = 0; j < 4; j++) {
                int n = n0 + wn + j * 16 + lr;
                int h = n >> 6, d = n & 63;
                float bv = bias[n];
                half4 w;
                #pragma unroll
                for (int r = 0; r < 4; r++) w[r] = (f16)(acc[i][j][r] + bv);
                *(half4*)(out + ((size_t)((b * 16 + h) * 64 + d)) * 2048 + s) = w;
            }
        }
    } else {
        int Sout = (mode == 0) ? 1024 : 2048;
        #pragma unroll
        for (int i = 0; i < 4; i++) {
            int mbase = m0 + wm + i * 16 + lg * 4;
            #pragma unroll
            for (int j = 0; j < 4; j++) {
                int n = n0 + wn + j * 16 + lr;
                int h = n >> 6, d = n & 63;
                float bv = bias[n];
                #pragma unroll
                for (int r = 0; r < 4; r++) {
                    int m = mbase + r;
                    int b = (mode == 0) ? (m >> 10) : (m >> 11);
                    int s = (mode == 0) ? (m & 1023) : (m & 2047);
                    out[((size_t)(b * 16 + h) * Sout + s) * 64 + d] = (f16)(acc[i][j][r] + bv);
                }
            }
        }
    }
}

// ---------------------------------------------------------------- flash attention (r22 dual-tile)
__device__ inline half8 pack_swap(float s0, float s1, float s2, float s3,
                                  float s4, float s5, float s6, float s7) {
    unsigned a0 = __builtin_bit_cast(unsigned, __builtin_amdgcn_cvt_pkrtz(s0, s1));
    unsigned b0 = __builtin_bit_cast(unsigned, __builtin_amdgcn_cvt_pkrtz(s4, s5));
    unsigned a1 = __builtin_bit_cast(unsigned, __builtin_amdgcn_cvt_pkrtz(s2, s3));
    unsigned b1 = __builtin_bit_cast(unsigned, __builtin_amdgcn_cvt_pkrtz(s6, s7));
    asm("v_permlane32_swap_b32 %0, %1" : "+v"(a0), "+v"(b0));
    asm("v_permlane32_swap_b32 %0, %1" : "+v"(a1), "+v"(b1));
    uint4v w = {a0, a1, b0, b1};
    return __builtin_bit_cast(half8, w);
}

__device__ inline half8 pack_noswap(float s0, float s1, float s2, float s3,
                                    float s4, float s5, float s6, float s7) {
    unsigned w0 = __builtin_bit_cast(unsigned, __builtin_amdgcn_cvt_pkrtz(s0, s1));
    unsigned w1 = __builtin_bit_cast(unsigned, __builtin_amdgcn_cvt_pkrtz(s2, s3));
    unsigned w2 = __builtin_bit_cast(unsigned, __builtin_amdgcn_cvt_pkrtz(s4, s5));
    unsigned w3 = __builtin_bit_cast(unsigned, __builtin_amdgcn_cvt_pkrtz(s6, s7));
    uint4v w = {w0, w1, w2, w3};
    return __builtin_bit_cast(half8, w);
}

__launch_bounds__(256)
__global__ void attn_kernel(const f16* __restrict__ Q, const f16* __restrict__ K,
                            const f16* __restrict__ Vt, const float* __restrict__ mask,
                            float* __restrict__ out) {
    __shared__ f16 Kt0[64 * 72], Kt1[64 * 72], Kt2[64 * 72], Kt3[64 * 72];
    __shared__ f16 Vt0[64 * 72], Vt1[64 * 72], Vt2[64 * 72], Vt3[64 * 72];
    __shared__ float maskLds[2048];

    const float LOG2E = 1.4426950408889634f;
    int tid = threadIdx.x;
    int wid = tid >> 6, lane = tid & 63;
    int l31 = lane & 31, l5 = lane >> 5;

    // XCD-bijective remap (r8-validated): 8 q-blocks of one bh per XCD
    int bid = blockIdx.x + 8 * blockIdx.y;   // grid (8,64) = 512
    int xcd = bid & 7, w = bid >> 3;
    int bh = xcd * 8 + (w >> 3);
    int xblk = w & 7;
    int b = bh >> 4;
    int q = xblk * 128 + wid * 32 + l31;

    // runtime probe of the 32x32x16 B-operand k-layout (flat vs two-block)
    half8 pa, pcode;
    #pragma unroll
    for (int j = 0; j < 8; j++) { pa[j] = (f16)0; pcode[j] = (f16)(8 * l5 + j); }
    if (l31 < 16 && (l31 >> 3) == l5) pa[l31 & 7] = (f16)1;
    floatx16 pd = __builtin_amdgcn_mfma_f32_32x32x16_f16(pa, pcode, (floatx16)0.f, 0, 0, 0);
    float r4 = __shfl(pd[0], 32);
    bool twoblk = (r4 > 6.0f);

    // stage mask * log2e - 8 into LDS (softmax offset folded into the C-init)
    const float* maskp = mask + b * 2048;
    for (int i = tid; i < 512; i += 256) {
        float4 mv = ((const float4*)maskp)[i];
        mv.x = mv.x * LOG2E - 8.0f; mv.y = mv.y * LOG2E - 8.0f;
        mv.z = mv.z * LOG2E - 8.0f; mv.w = mv.w * LOG2E - 8.0f;
        ((float4*)maskLds)[i] = mv;
    }

    // Q frags pre-scaled by 0.125*log2e, per probed B k-map
    const f16* qrow = Q + ((size_t)bh * 1024 + q) * 64;
    half8 qf[4];
    if (!twoblk) {
        #pragma unroll
        for (int ks = 0; ks < 4; ks++)
            qf[ks] = *(const half8*)(qrow + ks * 16 + l5 * 8);
    } else {
        #pragma unroll
        for (int ks = 0; ks < 4; ks++) {
            half4 lo = *(const half4*)(qrow + ks * 16 + 4 * l5);
            half4 hi = *(const half4*)(qrow + ks * 16 + 8 + 4 * l5);
            qf[ks][0] = lo[0]; qf[ks][1] = lo[1]; qf[ks][2] = lo[2]; qf[ks][3] = lo[3];
            qf[ks][4] = hi[0]; qf[ks][5] = hi[1]; qf[ks][6] = hi[2]; qf[ks][7] = hi[3];
        }
    }
    const f16 qs = (f16)(0.125f * 1.4426950408889634f);
    #pragma unroll
    for (int ks = 0; ks < 4; ks++)
        #pragma unroll
        for (int x = 0; x < 8; x++) qf[ks][x] *= qs;

    // ones A-row for MFMA l-sum
    half8 aones;
    #pragma unroll
    for (int j = 0; j < 8; j++) aones[j] = (l31 == 0) ? (f16)1 : (f16)0;

    floatx16 o0 = (floatx16)0.f, o1 = (floatx16)0.f, o2 = (floatx16)0.f;
    floatx16 sfA0, sfA1, sfB0, sfB1;

    int sr = tid >> 2, sc = (tid & 3) * 16;
    const f16* Ksrc = K + ((size_t)bh * 2048 + sr) * 64 + sc;
    const f16* Vsrc = Vt + ((size_t)(bh * 64 + sr)) * 2048 + sc;

    half8 rk0, rk1, rv0, rv1;

    #define ATT_LOAD(kv)                                                        \
        rk0 = *(const half8*)(Ksrc + (size_t)(kv) * 64);                        \
        rk1 = *(const half8*)(Ksrc + (size_t)(kv) * 64 + 8);                    \
        rv0 = *(const half8*)(Vsrc + (kv));                                     \
        rv1 = *(const half8*)(Vsrc + (kv) + 8);

    #define ATT_WRITE(KB, VB)                                                   \
        *(half8*)&KB[sr * 72 + sc]     = rk0;                                   \
        *(half8*)&KB[sr * 72 + sc + 8] = rk1;                                   \
        *(half8*)&VB[sr * 72 + sc]     = rv0;                                   \
        *(half8*)&VB[sr * 72 + sc + 8] = rv1;

    #define ATT_F(KB, S0, S1, kv0)                                              \
        {                                                                       \
            _Pragma("unroll")                                                   \
            for (int g = 0; g < 4; g++) {                                       \
                float4 mk0 = *(const float4*)&maskLds[(kv0) + 8 * g + 4 * l5];  \
                float4 mk1 = *(const float4*)&maskLds[(kv0) + 32 + 8 * g + 4 * l5]; \
                _Pragma("unroll")                                               \
                for (int i = 0; i < 4; i++) {                                   \
                    S0[4 * g + i] = ((const float*)&mk0)[i];                    \
                    S1[4 * g + i] = ((const float*)&mk1)[i];                    \
                }                                                               \
            }                                                                   \
            __builtin_amdgcn_s_setprio(1);                                      \
            _Pragma("unroll")                                                   \
            for (int ks = 0; ks < 4; ks++) {                                    \
                half8 k0 = *(const half8*)&KB[l31 * 72 + ks * 16 + l5 * 8];     \
                half8 k1 = *(const half8*)&KB[(32 + l31) * 72 + ks * 16 + l5 * 8]; \
                S0 = __builtin_amdgcn_mfma_f32_32x32x16_f16(k0, qf[ks], S0, 0, 0, 0); \
                S1 = __builtin_amdgcn_mfma_f32_32x32x16_f16(k1, qf[ks], S1, 0, 0, 0); \
            }                                                                   \
            __builtin_amdgcn_s_setprio(0);                                      \
        }

    #define ATT_E(S0, S1, PB)                                                   \
        {                                                                       \
            _Pragma("unroll")                                                   \
            for (int r = 0; r < 16; r++) {                                      \
                S0[r] = exp2f(S0[r]);                                           \
                S1[r] = exp2f(S1[r]);                                           \
            }                                                                   \
            if (!twoblk) {                                                      \
                PB[0] = pack_swap(S0[0], S0[1], S0[2], S0[3], S0[4], S0[5], S0[6], S0[7]); \
                PB[1] = pack_swap(S0[8], S0[9], S0[10], S0[11], S0[12], S0[13], S0[14], S0[15]); \
                PB[2] = pack_swap(S1[0], S1[1], S1[2], S1[3], S1[4], S1[5], S1[6], S1[7]); \
                PB[3] = pack_swap(S1[8], S1[9], S1[10], S1[11], S1[12], S1[13], S1[14], S1[15]); \
            } else {                                                            \
                PB[0] = pack_noswap(S0[0], S0[1], S0[2], S0[3], S0[4], S0[5], S0[6], S0[7]); \
                PB[1] = pack_noswap(S0[8], S0[9], S0[10], S0[11], S0[12], S0[13], S0[14], S0[15]); \
                PB[2] = pack_noswap(S1[0], S1[1], S1[2], S1[3], S1[4], S1[5], S1[6], S1[7]); \
                PB[3] = pack_noswap(S1[8], S1[9], S1[10], S1[11], S1[12], S1[13], S1[14], S1[15]); \
            }                                                                   \
        }

    #define ATT_P(VB, PB)                                                       \
        {                                                                       \
            __builtin_amdgcn_s_setprio(1);                                      \
            _Pragma("unroll")                                                   \
            for (int kb = 0; kb < 4; kb++) {                                    \
                half8 v0 = *(const half8*)&VB[l31 * 72 + kb * 16 + l5 * 8];     \
                half8 v1 = *(const half8*)&VB[(32 + l31) * 72 + kb * 16 + l5 * 8]; \
                o0 = __builtin_amdgcn_mfma_f32_32x32x16_f16(v0, PB[kb], o0, 0, 0, 0); \
                o1 = __builtin_amdgcn_mfma_f32_32x32x16_f16(v1, PB[kb], o1, 0, 0, 0); \
                o2 = __builtin_amdgcn_mfma_f32_32x32x16_f16(aones, PB[kb], o2, 0, 0, 0); \
            }                                                                   \
            __builtin_amdgcn_s_setprio(0);                                      \
        }

    #define ATT_BARRIER()                                                       \
        asm volatile("s_waitcnt lgkmcnt(0)" ::: "memory");                      \
        __builtin_amdgcn_sched_barrier(0);                                      \
        __builtin_amdgcn_s_barrier();

    // prologue: stage tiles 0,1,2 -> b0,b1,b2; regs hold tile 3
    ATT_LOAD(0);   ATT_WRITE(Kt0, Vt0);
    ATT_LOAD(64);  ATT_WRITE(Kt1, Vt1);
    ATT_LOAD(128); ATT_WRITE(Kt2, Vt2);
    ATT_LOAD(192);
    __syncthreads();
    ATT_F(Kt0, sfA0, sfA1, 0);   // sfA = F(tile 0)

    half8 pb[4];
    for (int g8 = 0; g8 < 8; g8++) {
        int t4 = g8 * 4;
        ATT_WRITE(Kt3, Vt3);
        if (t4 + 4 < 32) { ATT_LOAD((t4 + 4) * 64); }
        ATT_F(Kt1, sfB0, sfB1, (t4 + 1) * 64);
        ATT_E(sfA0, sfA1, pb);
        ATT_P(Vt0, pb);
        ATT_BARRIER();
        if (t4 + 4 < 32) { ATT_WRITE(Kt0, Vt0); }
        if (t4 + 5 < 32) { ATT_LOAD((t4 + 5) * 64); }
        ATT_F(Kt2, sfA0, sfA1, (t4 + 2) * 64);
        ATT_E(sfB0, sfB1, pb);
        ATT_P(Vt1, pb);
        ATT_BARRIER();
        if (t4 + 5 < 32) { ATT_WRITE(Kt1, Vt1); }
        if (t4 + 6 < 32) { ATT_LOAD((t4 + 6) * 64); }
        ATT_F(Kt3, sfB0, sfB1, (t4 + 3) * 64);
        ATT_E(sfA0, sfA1, pb);
        ATT_P(Vt2, pb);
        ATT_BARRIER();
        if (t4 + 6 < 32) { ATT_WRITE(Kt2, Vt2); }
        if (t4 + 7 < 32) { ATT_LOAD((t4 + 7) * 64); }
        if (t4 + 4 < 32) { ATT_F(Kt0, sfA0, sfA1, (t4 + 4) * 64); }
        ATT_E(sfB0, sfB1, pb);
        ATT_P(Vt3, pb);
        ATT_BARRIER();
    }

    #undef ATT_LOAD
    #undef ATT_WRITE
    #undef ATT_F
    #undef ATT_E
    #undef ATT_P
    #undef ATT_BARRIER

    float l_all = __shfl(o2[0], l31);
    int h = bh & 15;
    float inv = 1.f / l_all;
    float* orow = out + ((size_t)(b * 1024 + q)) * 1024 + h * 64;
    #pragma unroll
    for (int g = 0; g < 4; g++) {
        float4 r0 = {o0[4 * g] * inv, o0[4 * g + 1] * inv, o0[4 * g + 2] * inv, o0[4 * g + 3] * inv};
        float4 r1 = {o1[4 * g] * inv, o1[4 * g + 1] * inv, o1[4 * g + 2] * inv, o1[4 * g + 3] * inv};
        *(float4*)&orow[8 * g + 4 * l5]      = r0;
        *(float4*)&orow[32 + 8 * g + 4 * l5] = r1;
    }
}

// ---------------------------------------------------------------- launcher
extern "C" void kernel_launch(void* const* d_in, const int* in_sizes, int n_in,
                              void* d_out, int out_size, void* d_ws, size_t ws_size,
                              hipStream_t stream) {
    const float* hid  = (const float*)d_in[0];
    const float* enc  = (const float*)d_in[1];
    const float* mask = (const float*)d_in[2];
    const float* Wq   = (const float*)d_in[3];
    const float* bq   = (const float*)d_in[4];
    const float* Wk   = (const float*)d_in[5];
    const float* bk   = (const float*)d_in[6];
    const float* Wv   = (const float*)d_in[7];
    const float* bv   = (const float*)d_in[8];
    float* out = (float*)d_out;

    char* ws = (char*)d_ws;
    f16* Wtq  = (f16*)(ws + ((size_t)0 << 20));
    f16* Wtk  = (f16*)(ws + ((size_t)2 << 20));
    f16* Wtv  = (f16*)(ws + ((size_t)4 << 20));
    f16* Aall = (f16*)(ws + ((size_t)6 << 20));   // 16 MiB
    f16* Qw   = (f16*)(ws + ((size_t)22 << 20));  // 8 MiB
    f16* Kw   = (f16*)(ws + ((size_t)30 << 20));  // 16 MiB
    f16* Vtw  = (f16*)(ws + ((size_t)46 << 20));  // 16 MiB

    prep_kernel<<<7168, 256, 0, stream>>>(hid, enc, Wq, Wk, Wv, Wtq, Wtk, Wtv, Aall);

    qkv_gemm<<<dim3(64, 4, 3), 512, 0, stream>>>(Aall, Wtq, Wtk, Wtv, bq, bk, bv, Qw, Kw, Vtw);

    attn_kernel<<<dim3(8, 64), 256, 0, stream>>>(Qw, Kw, Vtw, mask, out);
}

// Round 24
// 140.000 us; speedup vs baseline: 1.0115x; 1.0115x over previous
//
#include <hip/hip_runtime.h>

// IncrementalRobertaSelfAttentionCross: B=4, Sq=1024, Skv=2048 (enc||dec), D=1024, H=16, HD=64
// Pipeline: prep (Wt transpose + A cast) -> fused QKV GEMM (128x128, static triple-buffer,
//           counted vmcnt(8)) -> flash attn (dual-tile F||E pipeline, fixed-m softmax,
//           MFMA l-sum, XCD remap).  [r22 configuration - measured best 140.0us]

typedef _Float16 f16;
typedef __attribute__((ext_vector_type(4))) _Float16 half4;
typedef __attribute__((ext_vector_type(8))) _Float16 half8;
typedef __attribute__((ext_vector_type(4))) float floatx4;
typedef __attribute__((ext_vector_type(16))) float floatx16;
typedef __attribute__((ext_vector_type(4))) unsigned int uint4v;

#define GLOAD16(gp, lp)                                                        \
    __builtin_amdgcn_global_load_lds(                                          \
        (const __attribute__((address_space(1))) void*)(gp),                   \
        (__attribute__((address_space(3))) void*)(lp), 16, 0, 0)

// ---------------------------------------------------------------- prep: W transposes + A cast
__global__ void prep_kernel(const float* __restrict__ hid, const float* __restrict__ enc,
                            const float* __restrict__ Wq, const float* __restrict__ Wk,
                            const float* __restrict__ Wv, f16* __restrict__ Wtq,
                            f16* __restrict__ Wtk, f16* __restrict__ Wtv,
                            f16* __restrict__ Aall) {
    int bid = blockIdx.x, tid = threadIdx.x;
    if (bid < 3072) {
        __shared__ float tile[32][33];
        int z = bid >> 10, xy = bid & 1023;
        const float* W = (z == 0) ? Wq : (z == 1) ? Wk : Wv;
        f16* Wt = (z == 0) ? Wtq : (z == 1) ? Wtk : Wtv;
        int n0 = (xy & 31) * 32, k0 = (xy >> 5) * 32;
        int tx = tid & 31, ty = tid >> 5;   // (32,8)
        #pragma unroll
        for (int i = 0; i < 32; i += 8)
            tile[ty + i][tx] = W[(k0 + ty + i) * 1024 + n0 + tx];
        __syncthreads();
        #pragma unroll
        for (int i = 0; i < 32; i += 8)
            Wt[(n0 + ty + i) * 1024 + k0 + tx] = (f16)tile[tx][ty + i];
    } else {
        int t = (bid - 3072) * 256 + tid;
        int rowg = t >> 7, col = (t & 127) * 8;
        int b = rowg >> 11, r = rowg & 2047;
        const float* src = (r < 1024 ? enc + ((size_t)b * 1024 + r) * 1024
                                     : hid + ((size_t)b * 1024 + (r - 1024)) * 1024) + col;
        float4 v0 = *(const float4*)src, v1 = *(const float4*)(src + 4);
        half8 o;
        o[0] = (f16)v0.x; o[1] = (f16)v0.y; o[2] = (f16)v0.z; o[3] = (f16)v0.w;
        o[4] = (f16)v1.x; o[5] = (f16)v1.y; o[6] = (f16)v1.z; o[7] = (f16)v1.w;
        *(half8*)(Aall + (size_t)rowg * 1024 + col) = o;
    }
}

// ---------------------------------------------------------------- fused QKV GEMM (r17)
__launch_bounds__(256)
__global__ void qkv_gemm(const f16* __restrict__ Aall,
                         const f16* __restrict__ Wtq, const f16* __restrict__ Wtk,
                         const f16* __restrict__ Wtv,
                         const float* __restrict__ bq, const float* __restrict__ bk,
                         const float* __restrict__ bv,
                         f16* __restrict__ Qw, f16* __restrict__ Kw, f16* __restrict__ Vtw) {
    int mode = blockIdx.z;
    if (mode == 0 && blockIdx.x >= 32) return;   // uniform per block: barrier-safe
    __shared__ f16 As0[128 * 32];
    __shared__ f16 Bs0[128 * 32];
    __shared__ f16 As1[128 * 32];
    __shared__ f16 Bs1[128 * 32];
    __shared__ f16 As2[128 * 32];
    __shared__ f16 Bs2[128 * 32];

    const f16* Wt = (mode == 0) ? Wtq : (mode == 1) ? Wtk : Wtv;
    const float* bias = (mode == 0) ? bq : (mode == 1) ? bk : bv;
    f16* out = (mode == 0) ? Qw : (mode == 1) ? Kw : Vtw;

    int tid = threadIdx.x;
    int m0 = blockIdx.x * 128, n0 = blockIdx.y * 128;
    int wid = tid >> 6, lane = tid & 63;
    int wm = (wid >> 1) * 64, wn = (wid & 1) * 64;
    int lr = lane & 15, lg = lane >> 4;

    floatx4 acc[4][4];
    #pragma unroll
    for (int i = 0; i < 4; i++)
        #pragma unroll
        for (int j = 0; j < 4; j++) acc[i][j] = (floatx4)(0.f);

    int trow = tid >> 2;
    int tcol = (((tid & 3) ^ ((tid >> 3) & 3))) * 8;
    const f16 *a0g, *a1g;
    {
        int mA0 = m0 + trow, mA1 = mA0 + 64;
        if (mode == 0) {
            int b0 = mA0 >> 10, b1 = mA1 >> 10;
            a0g = Aall + ((size_t)(b0 * 2048 + 1024 + (mA0 & 1023))) * 1024 + tcol;
            a1g = Aall + ((size_t)(b1 * 2048 + 1024 + (mA1 & 1023))) * 1024 + tcol;
        } else {
            a0g = Aall + (size_t)mA0 * 1024 + tcol;
            a1g = Aall + (size_t)mA1 * 1024 + tcol;
        }
    }
    const f16* b0g = Wt + (size_t)(n0 + trow) * 1024 + tcol;
    const f16* b1g = Wt + (size_t)(n0 + trow + 64) * 1024 + tcol;

    int rcol = (lg ^ ((lr >> 1) & 3)) * 8;

    #define QKV_STAGE(off, Abuf, Bbuf)                    \
        GLOAD16(a0g + (off), &Abuf[tid * 8]);             \
        GLOAD16(a1g + (off), &Abuf[tid * 8 + 2048]);      \
        GLOAD16(b0g + (off), &Bbuf[tid * 8]);             \
        GLOAD16(b1g + (off), &Bbuf[tid * 8 + 2048]);

    #define QKV_COMPUTE(Abuf, Bbuf)                                                       \
        {                                                                                 \
            half8 a[4], bf[4];                                                            \
            _Pragma("unroll")                                                             \
            for (int i = 0; i < 4; i++)                                                   \
                a[i] = *(const half8*)&Abuf[(wm + i * 16 + lr) * 32 + rcol];              \
            _Pragma("unroll")                                                             \
            for (int j = 0; j < 4; j++)                                                   \
                bf[j] = *(const half8*)&Bbuf[(wn + j * 16 + lr) * 32 + rcol];             \
            __builtin_amdgcn_s_setprio(1);                                                \
            _Pragma("unroll")                                                             \
            for (int i = 0; i < 4; i++)                                                   \
                _Pragma("unroll")                                                         \
                for (int j = 0; j < 4; j++)                                               \
                    acc[i][j] = __builtin_amdgcn_mfma_f32_16x16x32_f16(a[i], bf[j],       \
                                                                      acc[i][j], 0, 0, 0);\
            __builtin_amdgcn_s_setprio(0);                                                \
        }

    QKV_STAGE(0,  As0, Bs0);
    QKV_STAGE(32, As1, Bs1);
    QKV_STAGE(64, As2, Bs2);
    asm volatile("s_waitcnt vmcnt(8)" ::: "memory");
    __builtin_amdgcn_s_barrier();

    for (int k0 = 0; k0 < 960; k0 += 96) {
        QKV_COMPUTE(As0, Bs0);
        asm volatile("s_waitcnt lgkmcnt(0)" ::: "memory");
        __builtin_amdgcn_s_barrier();
        QKV_STAGE(k0 + 96, As0, Bs0);
        asm volatile("s_waitcnt vmcnt(8)" ::: "memory");
        __builtin_amdgcn_s_barrier();

        QKV_COMPUTE(As1, Bs1);
        asm volatile("s_waitcnt lgkmcnt(0)" ::: "memory");
        __builtin_amdgcn_s_barrier();
        QKV_STAGE(k0 + 128, As1, Bs1);
        asm volatile("s_waitcnt vmcnt(8)" ::: "memory");
        __builtin_amdgcn_s_barrier();

        QKV_COMPUTE(As2, Bs2);
        asm volatile("s_waitcnt lgkmcnt(0)" ::: "memory");
        __builtin_amdgcn_s_barrier();
        if (k0 + 160 < 1024) {
            QKV_STAGE(k0 + 160, As2, Bs2);
            asm volatile("s_waitcnt vmcnt(8)" ::: "memory");
        } else {
            asm volatile("s_waitcnt vmcnt(4)" ::: "memory");
        }
        __builtin_amdgcn_s_barrier();
    }

    QKV_COMPUTE(As0, Bs0);
    asm volatile("s_waitcnt vmcnt(0)" ::: "memory");
    __builtin_amdgcn_s_barrier();
    QKV_COMPUTE(As1, Bs1);

    #undef QKV_STAGE
    #undef QKV_COMPUTE

    if (mode == 2) {
        #pragma unroll
        for (int i = 0; i < 4; i++) {
            int mbase = m0 + wm + i * 16 + lg * 4;
            int b = mbase >> 11, s = mbase & 2047;
            #pragma unroll
            for (int j = 0; j < 4; j++) {
                int n = n0 + wn + j * 16 + lr;
                int h = n >> 6, d = n & 63;
                float bv = bias[n];
                half4 w;
                #pragma unroll
                for (int r = 0; r < 4; r++) w[r] = (f16)(acc[i][j][r] + bv);
                *(half4*)(out + ((size_t)((b * 16 + h) * 64 + d)) * 2048 + s) = w;
            }
        }
    } else {
        int Sout = (mode == 0) ? 1024 : 2048;
        #pragma unroll
        for (int i = 0; i < 4; i++) {
            int mbase = m0 + wm + i * 16 + lg * 4;
            #pragma unroll
            for (int j = 0; j < 4; j++) {
                int n = n0 + wn + j * 16 + lr;
                int h = n >> 6, d = n & 63;
                float bv = bias[n];
                #pragma unroll
                for (int r = 0; r < 4; r++) {
                    int m = mbase + r;
                    int b = (mode == 0) ? (m >> 10) : (m >> 11);
                    int s = (mode == 0) ? (m & 1023) : (m & 2047);
                    out[((size_t)(b * 16 + h) * Sout + s) * 64 + d] = (f16)(acc[i][j][r] + bv);
                }
            }
        }
    }
}

// ---------------------------------------------------------------- flash attention (dual-tile)
__device__ inline half8 pack_swap(float s0, float s1, float s2, float s3,
                                  float s4, float s5, float s6, float s7) {
    unsigned a0 = __builtin_bit_cast(unsigned, __builtin_amdgcn_cvt_pkrtz(s0, s1));
    unsigned b0 = __builtin_bit_cast(unsigned, __builtin_amdgcn_cvt_pkrtz(s4, s5));
    unsigned a1 = __builtin_bit_cast(unsigned, __builtin_amdgcn_cvt_pkrtz(s2, s3));
    unsigned b1 = __builtin_bit_cast(unsigned, __builtin_amdgcn_cvt_pkrtz(s6, s7));
    asm("v_permlane32_swap_b32 %0, %1" : "+v"(a0), "+v"(b0));
    asm("v_permlane32_swap_b32 %0, %1" : "+v"(a1), "+v"(b1));
    uint4v w = {a0, a1, b0, b1};
    return __builtin_bit_cast(half8, w);
}

__device__ inline half8 pack_noswap(float s0, float s1, float s2, float s3,
                                    float s4, float s5, float s6, float s7) {
    unsigned w0 = __builtin_bit_cast(unsigned, __builtin_amdgcn_cvt_pkrtz(s0, s1));
    unsigned w1 = __builtin_bit_cast(unsigned, __builtin_amdgcn_cvt_pkrtz(s2, s3));
    unsigned w2 = __builtin_bit_cast(unsigned, __builtin_amdgcn_cvt_pkrtz(s4, s5));
    unsigned w3 = __builtin_bit_cast(unsigned, __builtin_amdgcn_cvt_pkrtz(s6, s7));
    uint4v w = {w0, w1, w2, w3};
    return __builtin_bit_cast(half8, w);
}

__launch_bounds__(256)
__global__ void attn_kernel(const f16* __restrict__ Q, const f16* __restrict__ K,
                            const f16* __restrict__ Vt, const float* __restrict__ mask,
                            float* __restrict__ out) {
    __shared__ f16 Kt0[64 * 72], Kt1[64 * 72], Kt2[64 * 72], Kt3[64 * 72];
    __shared__ f16 Vt0[64 * 72], Vt1[64 * 72], Vt2[64 * 72], Vt3[64 * 72];
    __shared__ float maskLds[2048];

    const float LOG2E = 1.4426950408889634f;
    int tid = threadIdx.x;
    int wid = tid >> 6, lane = tid & 63;
    int l31 = lane & 31, l5 = lane >> 5;

    // XCD-bijective remap (r8-validated): 8 q-blocks of one bh per XCD
    int bid = blockIdx.x + 8 * blockIdx.y;   // grid (8,64) = 512
    int xcd = bid & 7, w = bid >> 3;
    int bh = xcd * 8 + (w >> 3);
    int xblk = w & 7;
    int b = bh >> 4;
    int q = xblk * 128 + wid * 32 + l31;

    // runtime probe of the 32x32x16 B-operand k-layout (flat vs two-block)
    half8 pa, pcode;
    #pragma unroll
    for (int j = 0; j < 8; j++) { pa[j] = (f16)0; pcode[j] = (f16)(8 * l5 + j); }
    if (l31 < 16 && (l31 >> 3) == l5) pa[l31 & 7] = (f16)1;
    floatx16 pd = __builtin_amdgcn_mfma_f32_32x32x16_f16(pa, pcode, (floatx16)0.f, 0, 0, 0);
    float r4 = __shfl(pd[0], 32);
    bool twoblk = (r4 > 6.0f);

    // stage mask * log2e - 8 into LDS (softmax offset folded into the C-init)
    const float* maskp = mask + b * 2048;
    for (int i = tid; i < 512; i += 256) {
        float4 mv = ((const float4*)maskp)[i];
        mv.x = mv.x * LOG2E - 8.0f; mv.y = mv.y * LOG2E - 8.0f;
        mv.z = mv.z * LOG2E - 8.0f; mv.w = mv.w * LOG2E - 8.0f;
        ((float4*)maskLds)[i] = mv;
    }

    // Q frags pre-scaled by 0.125*log2e, per probed B k-map
    const f16* qrow = Q + ((size_t)bh * 1024 + q) * 64;
    half8 qf[4];
    if (!twoblk) {
        #pragma unroll
        for (int ks = 0; ks < 4; ks++)
            qf[ks] = *(const half8*)(qrow + ks * 16 + l5 * 8);
    } else {
        #pragma unroll
        for (int ks = 0; ks < 4; ks++) {
            half4 lo = *(const half4*)(qrow + ks * 16 + 4 * l5);
            half4 hi = *(const half4*)(qrow + ks * 16 + 8 + 4 * l5);
            qf[ks][0] = lo[0]; qf[ks][1] = lo[1]; qf[ks][2] = lo[2]; qf[ks][3] = lo[3];
            qf[ks][4] = hi[0]; qf[ks][5] = hi[1]; qf[ks][6] = hi[2]; qf[ks][7] = hi[3];
        }
    }
    const f16 qs = (f16)(0.125f * 1.4426950408889634f);
    #pragma unroll
    for (int ks = 0; ks < 4; ks++)
        #pragma unroll
        for (int x = 0; x < 8; x++) qf[ks][x] *= qs;

    // ones A-row for MFMA l-sum
    half8 aones;
    #pragma unroll
    for (int j = 0; j < 8; j++) aones[j] = (l31 == 0) ? (f16)1 : (f16)0;

    floatx16 o0 = (floatx16)0.f, o1 = (floatx16)0.f, o2 = (floatx16)0.f;
    floatx16 sfA0, sfA1, sfB0, sfB1;

    int sr = tid >> 2, sc = (tid & 3) * 16;
    const f16* Ksrc = K + ((size_t)bh * 2048 + sr) * 64 + sc;
    const f16* Vsrc = Vt + ((size_t)(bh * 64 + sr)) * 2048 + sc;

    half8 rk0, rk1, rv0, rv1;

    #define ATT_LOAD(kv)                                                        \
        rk0 = *(const half8*)(Ksrc + (size_t)(kv) * 64);                        \
        rk1 = *(const half8*)(Ksrc + (size_t)(kv) * 64 + 8);                    \
        rv0 = *(const half8*)(Vsrc + (kv));                                     \
        rv1 = *(const half8*)(Vsrc + (kv) + 8);

    #define ATT_WRITE(KB, VB)                                                   \
        *(half8*)&KB[sr * 72 + sc]     = rk0;                                   \
        *(half8*)&KB[sr * 72 + sc + 8] = rk1;                                   \
        *(half8*)&VB[sr * 72 + sc]     = rv0;                                   \
        *(half8*)&VB[sr * 72 + sc + 8] = rv1;

    #define ATT_F(KB, S0, S1, kv0)                                              \
        {                                                                       \
            _Pragma("unroll")                                                   \
            for (int g = 0; g < 4; g++) {                                       \
                float4 mk0 = *(const float4*)&maskLds[(kv0) + 8 * g + 4 * l5];  \
                float4 mk1 = *(const float4*)&maskLds[(kv0) + 32 + 8 * g + 4 * l5]; \
                _Pragma("unroll")                                               \
                for (int i = 0; i < 4; i++) {                                   \
                    S0[4 * g + i] = ((const float*)&mk0)[i];                    \
                    S1[4 * g + i] = ((const float*)&mk1)[i];                    \
                }                                                               \
            }                                                                   \
            __builtin_amdgcn_s_setprio(1);                                      \
            _Pragma("unroll")                                                   \
            for (int ks = 0; ks < 4; ks++) {                                    \
                half8 k0 = *(const half8*)&KB[l31 * 72 + ks * 16 + l5 * 8];     \
                half8 k1 = *(const half8*)&KB[(32 + l31) * 72 + ks * 16 + l5 * 8]; \
                S0 = __builtin_amdgcn_mfma_f32_32x32x16_f16(k0, qf[ks], S0, 0, 0, 0); \
                S1 = __builtin_amdgcn_mfma_f32_32x32x16_f16(k1, qf[ks], S1, 0, 0, 0); \
            }                                                                   \
            __builtin_amdgcn_s_setprio(0);                                      \
        }

    #define ATT_E(S0, S1, PB)                                                   \
        {                                                                       \
            _Pragma("unroll")                                                   \
            for (int r = 0; r < 16; r++) {                                      \
                S0[r] = exp2f(S0[r]);                                           \
                S1[r] = exp2f(S1[r]);                                           \
            }                                                                   \
            if (!twoblk) {                                                      \
                PB[0] = pack_swap(S0[0], S0[1], S0[2], S0[3], S0[4], S0[5], S0[6], S0[7]); \
                PB[1] = pack_swap(S0[8], S0[9], S0[10], S0[11], S0[12], S0[13], S0[14], S0[15]); \
                PB[2] = pack_swap(S1[0], S1[1], S1[2], S1[3], S1[4], S1[5], S1[6], S1[7]); \
                PB[3] = pack_swap(S1[8], S1[9], S1[10], S1[11], S1[12], S1[13], S1[14], S1[15]); \
            } else {                                                            \
                PB[0] = pack_noswap(S0[0], S0[1], S0[2], S0[3], S0[4], S0[5], S0[6], S0[7]); \
                PB[1] = pack_noswap(S0[8], S0[9], S0[10], S0[11], S0[12], S0[13], S0[14], S0[15]); \
                PB[2] = pack_noswap(S1[0], S1[1], S1[2], S1[3], S1[4], S1[5], S1[6], S1[7]); \
                PB[3] = pack_noswap(S1[8], S1[9], S1[10], S1[11], S1[12], S1[13], S1[14], S1[15]); \
            }                                                                   \
        }

    #define ATT_P(VB, PB)                                                       \
        {                                                                       \
            __builtin_amdgcn_s_setprio(1);                                      \
            _Pragma("unroll")                                                   \
            for (int kb = 0; kb < 4; kb++) {                                    \
                half8 v0 = *(const half8*)&VB[l31 * 72 + kb * 16 + l5 * 8];     \
                half8 v1 = *(const half8*)&VB[(32 + l31) * 72 + kb * 16 + l5 * 8]; \
                o0 = __builtin_amdgcn_mfma_f32_32x32x16_f16(v0, PB[kb], o0, 0, 0, 0); \
                o1 = __builtin_amdgcn_mfma_f32_32x32x16_f16(v1, PB[kb], o1, 0, 0, 0); \
                o2 = __builtin_amdgcn_mfma_f32_32x32x16_f16(aones, PB[kb], o2, 0, 0, 0); \
            }                                                                   \
            __builtin_amdgcn_s_setprio(0);                                      \
        }

    #define ATT_BARRIER()                                                       \
        asm volatile("s_waitcnt lgkmcnt(0)" ::: "memory");                      \
        __builtin_amdgcn_sched_barrier(0);                                      \
        __builtin_amdgcn_s_barrier();

    // prologue: stage tiles 0,1,2 -> b0,b1,b2; regs hold tile 3
    ATT_LOAD(0);   ATT_WRITE(Kt0, Vt0);
    ATT_LOAD(64);  ATT_WRITE(Kt1, Vt1);
    ATT_LOAD(128); ATT_WRITE(Kt2, Vt2);
    ATT_LOAD(192);
    __syncthreads();
    ATT_F(Kt0, sfA0, sfA1, 0);   // sfA = F(tile 0)

    half8 pb[4];
    for (int g8 = 0; g8 < 8; g8++) {
        int t4 = g8 * 4;
        ATT_WRITE(Kt3, Vt3);
        if (t4 + 4 < 32) { ATT_LOAD((t4 + 4) * 64); }
        ATT_F(Kt1, sfB0, sfB1, (t4 + 1) * 64);
        ATT_E(sfA0, sfA1, pb);
        ATT_P(Vt0, pb);
        ATT_BARRIER();
        if (t4 + 4 < 32) { ATT_WRITE(Kt0, Vt0); }
        if (t4 + 5 < 32) { ATT_LOAD((t4 + 5) * 64); }
        ATT_F(Kt2, sfA0, sfA1, (t4 + 2) * 64);
        ATT_E(sfB0, sfB1, pb);
        ATT_P(Vt1, pb);
        ATT_BARRIER();
        if (t4 + 5 < 32) { ATT_WRITE(Kt1, Vt1); }
        if (t4 + 6 < 32) { ATT_LOAD((t4 + 6) * 64); }
        ATT_F(Kt3, sfB0, sfB1, (t4 + 3) * 64);
        ATT_E(sfA0, sfA1, pb);
        ATT_P(Vt2, pb);
        ATT_BARRIER();
        if (t4 + 6 < 32) { ATT_WRITE(Kt2, Vt2); }
        if (t4 + 7 < 32) { ATT_LOAD((t4 + 7) * 64); }
        if (t4 + 4 < 32) { ATT_F(Kt0, sfA0, sfA1, (t4 + 4) * 64); }
        ATT_E(sfB0, sfB1, pb);
        ATT_P(Vt3, pb);
        ATT_BARRIER();
    }

    #undef ATT_LOAD
    #undef ATT_WRITE
    #undef ATT_F
    #undef ATT_E
    #undef ATT_P
    #undef ATT_BARRIER

    float l_all = __shfl(o2[0], l31);
    int h = bh & 15;
    float inv = 1.f / l_all;
    float* orow = out + ((size_t)(b * 1024 + q)) * 1024 + h * 64;
    #pragma unroll
    for (int g = 0; g < 4; g++) {
        float4 r0 = {o0[4 * g] * inv, o0[4 * g + 1] * inv, o0[4 * g + 2] * inv, o0[4 * g + 3] * inv};
        float4 r1 = {o1[4 * g] * inv, o1[4 * g + 1] * inv, o1[4 * g + 2] * inv, o1[4 * g + 3] * inv};
        *(float4*)&orow[8 * g + 4 * l5]      = r0;
        *(float4*)&orow[32 + 8 * g + 4 * l5] = r1;
    }
}

// ---------------------------------------------------------------- launcher
extern "C" void kernel_launch(void* const* d_in, const int* in_sizes, int n_in,
                              void* d_out, int out_size, void* d_ws, size_t ws_size,
                              hipStream_t stream) {
    const float* hid  = (const float*)d_in[0];
    const float* enc  = (const float*)d_in[1];
    const float* mask = (const float*)d_in[2];
    const float* Wq   = (const float*)d_in[3];
    const float* bq   = (const float*)d_in[4];
    const float* Wk   = (const float*)d_in[5];
    const float* bk   = (const float*)d_in[6];
    const float* Wv   = (const float*)d_in[7];
    const float* bv   = (const float*)d_in[8];
    float* out = (float*)d_out;

    char* ws = (char*)d_ws;
    f16* Wtq  = (f16*)(ws + ((size_t)0 << 20));
    f16* Wtk  = (f16*)(ws + ((size_t)2 << 20));
    f16* Wtv  = (f16*)(ws + ((size_t)4 << 20));
    f16* Aall = (f16*)(ws + ((size_t)6 << 20));   // 16 MiB
    f16* Qw   = (f16*)(ws + ((size_t)22 << 20));  // 8 MiB
    f16* Kw   = (f16*)(ws + ((size_t)30 << 20));  // 16 MiB
    f16* Vtw  = (f16*)(ws + ((size_t)46 << 20));  // 16 MiB

    prep_kernel<<<7168, 256, 0, stream>>>(hid, enc, Wq, Wk, Wv, Wtq, Wtk, Wtv, Aall);

    qkv_gemm<<<dim3(64, 8, 3), 256, 0, stream>>>(Aall, Wtq, Wtk, Wtv, bq, bk, bv, Qw, Kw, Vtw);

    attn_kernel<<<dim3(8, 64), 256, 0, stream>>>(Qw, Kw, Vtw, mask, out);
}